// Round 4
// baseline (1929.190 us; speedup 1.0000x reference)
//
#include <hip/hip_runtime.h>
#include <hip/hip_bf16.h>
#include <float.h>
#include <limits.h>

// Problem constants (fixed by reference setup_inputs)
#define BATCH 8
#define NN    4096
#define CC    256
#define KNN_K 4
#define NKE   (NN * KNN_K)

// Tiling: block = 256 threads (4 waves = 1 wave/EU). Block tile 64 rows x 256
// cols; thread grid 8(rg) x 32(cg); per-thread register tile 8x8 (strided).
// 256-thread blocks are the key: a 512-thread block forces >=2 waves/EU and
// the backend then caps VGPRs at 128 (R2/R3 showed ~900MB of spill traffic).
// With (256,1) the cap is 512; demand ~220 -> no spill, and at <=256 VGPR the
// HW still fits 2 blocks/CU (8 waves) for staging-latency overlap.
#define TI 64
#define TJ 256
#define TK 32
#define LW 36     // LDS row stride in words (32 + 4 pad)

// ---------------------------------------------------------------------------
// Kernel 1: inverse L2 norm per row. One 64-lane wave per row, 4 rows/block.
// ---------------------------------------------------------------------------
__global__ void knn_norm_kernel(const float* __restrict__ x, float* __restrict__ invn) {
    const int row  = blockIdx.x * 4 + (threadIdx.x >> 6);
    const int lane = threadIdx.x & 63;
    const float4 v = *(const float4*)(x + (size_t)row * CC + lane * 4);
    float ss = v.x * v.x + v.y * v.y + v.z * v.z + v.w * v.w;
    #pragma unroll
    for (int off = 32; off > 0; off >>= 1) ss += __shfl_down(ss, off, 64);
    if (lane == 0) invn[row] = 1.0f / sqrtf(ss);
}

// top-k ordering predicate matching jax.lax.top_k: value desc, ties -> smaller index
__device__ __forceinline__ bool knn_better(float v, int j, float v2, int j2) {
    return (v > v2) || (v == v2 && j < j2);
}

// insert candidate into sorted-descending top-4 (registers, fully unrolled)
__device__ __forceinline__ void knn_insert(float v, int j, float (&tv)[4], int (&tj)[4]) {
    if (knn_better(v, j, tv[3], tj[3])) {
        tv[3] = v; tj[3] = j;
        #pragma unroll
        for (int s = 3; s > 0; --s) {
            if (knn_better(tv[s], tj[s], tv[s - 1], tj[s - 1])) {
                float fv = tv[s]; tv[s] = tv[s - 1]; tv[s - 1] = fv;
                int   fj = tj[s]; tj[s] = tj[s - 1]; tj[s - 1] = fj;
            }
        }
    }
}

// ---------------------------------------------------------------------------
// Kernel 2: 64x256 tile, 8x8 per-thread, broadcast-heavy LDS reads,
// shfl-butterfly top-4 merge. 2 blocks/CU hide staging latency.
// ---------------------------------------------------------------------------
__global__ __launch_bounds__(256, 1) void knn_main_kernel(const float* __restrict__ x,
                                                          const float* __restrict__ invn,
                                                          float* __restrict__ out) {
    __shared__ __align__(16) float As[TI * LW];   //  9.0 KB
    __shared__ __align__(16) float Bs[TJ * LW];   // 36.0 KB  (45 KB total)

    const int tid = threadIdx.x;
    const int b   = blockIdx.x >> 6;         // 64 i-tiles per batch
    const int it  = blockIdx.x & 63;
    const int i0  = it * TI;
    const float* xb   = x    + (size_t)b * NN * CC;
    const float* invb = invn + (size_t)b * NN;
    const int rg = tid >> 5;                 // 0..7 ; wave = {2 rg values} x all 32 cg
    const int cg = tid & 31;                 // 0..31

    float vni[8];
    #pragma unroll
    for (int ri = 0; ri < 8; ++ri) vni[ri] = invb[i0 + rg + 8 * ri];

    // per-thread sorted top-4 per owned row, kept for the whole kernel
    float tv[8][4];
    int   tjx[8][4];
    #pragma unroll
    for (int ri = 0; ri < 8; ++ri)
        #pragma unroll
        for (int s = 0; s < 4; ++s) { tv[ri][s] = -INFINITY; tjx[ri][s] = INT_MAX; }

    // staging decomposition: float4 id p -> row = p>>3, k4 = p&7 (8 float4 per row)
    const int s_row = tid >> 3;              // 0..31
    const int s_k4  = tid & 7;

    for (int jt = 0; jt < NN / TJ; ++jt) {   // 16 j-tiles
        const int j0 = jt * TJ;
        float vnj[8];
        #pragma unroll
        for (int ci = 0; ci < 8; ++ci) vnj[ci] = invb[j0 + cg + 32 * ci];

        float acc[8][8];
        #pragma unroll
        for (int ri = 0; ri < 8; ++ri)
            #pragma unroll
            for (int ci = 0; ci < 8; ++ci) acc[ri][ci] = 0.0f;

        for (int kt = 0; kt < CC / TK; ++kt) {   // 8 k-chunks
            const int ko = kt * TK + s_k4 * 4;
            // issue global loads before the barrier (no LDS dependency)
            float4 pa[2], pb[8];
            #pragma unroll
            for (int l = 0; l < 2; ++l)
                pa[l] = *(const float4*)(xb + (size_t)(i0 + s_row + 32 * l) * CC + ko);
            #pragma unroll
            for (int l = 0; l < 8; ++l)
                pb[l] = *(const float4*)(xb + (size_t)(j0 + s_row + 32 * l) * CC + ko);
            __syncthreads();   // prior-iter LDS reads done before overwrite
            #pragma unroll
            for (int l = 0; l < 2; ++l)
                *(float4*)(As + (s_row + 32 * l) * LW + s_k4 * 4) = pa[l];
            #pragma unroll
            for (int l = 0; l < 8; ++l)
                *(float4*)(Bs + (s_row + 32 * l) * LW + s_k4 * 4) = pb[l];
            __syncthreads();

            #pragma unroll
            for (int k4 = 0; k4 < TK / 4; ++k4) {
                float4 b4[8];
                #pragma unroll
                for (int ci = 0; ci < 8; ++ci)     // 32 distinct addrs/wave, phase-clean
                    b4[ci] = *(const float4*)(Bs + (cg + 32 * ci) * LW + k4 * 4);
                #pragma unroll
                for (int ri = 0; ri < 8; ++ri) {   // 2 distinct addrs/wave -> broadcast
                    const float4 a4 = *(const float4*)(As + (rg + 8 * ri) * LW + k4 * 4);
                    #pragma unroll
                    for (int ci = 0; ci < 8; ++ci) {
                        acc[ri][ci] = fmaf(a4.x, b4[ci].x, acc[ri][ci]);
                        acc[ri][ci] = fmaf(a4.y, b4[ci].y, acc[ri][ci]);
                        acc[ri][ci] = fmaf(a4.z, b4[ci].z, acc[ri][ci]);
                        acc[ri][ci] = fmaf(a4.w, b4[ci].w, acc[ri][ci]);
                    }
                }
            }
        }

        // ---- top-k update for this j-tile (registers only) ----
        #pragma unroll
        for (int ri = 0; ri < 8; ++ri) {
            const int ig = i0 + rg + 8 * ri;
            #pragma unroll
            for (int ci = 0; ci < 8; ++ci) {
                const int jg = j0 + cg + 32 * ci;
                if (jg == ig) continue;            // diagonal = -inf in reference
                const float v = acc[ri][ci] * vni[ri] * vnj[ci];
                knn_insert(v, jg, tv[ri], tjx[ri]);
            }
        }
    }

    // ---- butterfly merge across the 32 cg lanes (same wave half) ----
    #pragma unroll
    for (int m = 1; m <= 16; m <<= 1) {
        #pragma unroll
        for (int ri = 0; ri < 8; ++ri) {
            float pv[4]; int pj[4];
            #pragma unroll
            for (int s = 0; s < 4; ++s) {
                pv[s] = __shfl_xor(tv[ri][s],  m, 64);
                pj[s] = __shfl_xor(tjx[ri][s], m, 64);
            }
            #pragma unroll
            for (int s = 0; s < 4; ++s) knn_insert(pv[s], pj[s], tv[ri], tjx[ri]);
        }
    }

    // lane cg==0 of each rg holds the final top-4 for its 8 rows
    if (cg == 0) {
        float* o_src = out + (size_t)b * 2 * NKE;
        float* o_tgt = o_src + NKE;
        float* o_w   = out + (size_t)BATCH * 2 * NKE + (size_t)b * NKE;
        #pragma unroll
        for (int ri = 0; ri < 8; ++ri) {
            const int ig = i0 + rg + 8 * ri;
            #pragma unroll
            for (int s = 0; s < 4; ++s) {
                o_src[ig * KNN_K + s] = (float)ig;
                o_tgt[ig * KNN_K + s] = (float)tjx[ri][s];
                o_w[ig * KNN_K + s]   = tv[ri][s];
            }
        }
    }
}

extern "C" void kernel_launch(void* const* d_in, const int* in_sizes, int n_in,
                              void* d_out, int out_size, void* d_ws, size_t ws_size,
                              hipStream_t stream) {
    const float* x    = (const float*)d_in[0];
    float*       out  = (float*)d_out;
    float*       invn = (float*)d_ws;   // 8*4096 floats = 128 KB scratch

    knn_norm_kernel<<<(BATCH * NN) / 4, 256, 0, stream>>>(x, invn);
    knn_main_kernel<<<BATCH * (NN / TI), 256, 0, stream>>>(x, invn, out);
}

// Round 5
// 1249.965 us; speedup vs baseline: 1.5434x; 1.5434x over previous
//
#include <hip/hip_runtime.h>
#include <hip/hip_bf16.h>
#include <float.h>
#include <limits.h>

// Problem constants (fixed by reference setup_inputs)
#define BATCH 8
#define NN    4096
#define CC    256
#define KNN_K 4
#define NKE   (NN * KNN_K)

// Tiling: block = 256 threads (4 waves). Block tile 64 rows x 128 cols.
// Thread grid 16(rg) x 16(cg); per-thread register tile 4 rows x 8 cols.
// R4 post-mortem: demand ~240 regs (acc64 + topk64 + prefetch40 + b4 32)
// exceeds what the allocator will commit -> tv/tjx spilled to scratch
// (219MB WRITE_SIZE, 900-cyc dependent chains, VALU 38%). This config
// halves acc and topk state (peak ~160 regs) so nothing spills.
#define TI 64
#define TJ 128
#define TK 32
#define LW 36     // LDS row stride in words (32 + 4 pad)

// ---------------------------------------------------------------------------
// Kernel 1: inverse L2 norm per row. One 64-lane wave per row, 4 rows/block.
// ---------------------------------------------------------------------------
__global__ void knn_norm_kernel(const float* __restrict__ x, float* __restrict__ invn) {
    const int row  = blockIdx.x * 4 + (threadIdx.x >> 6);
    const int lane = threadIdx.x & 63;
    const float4 v = *(const float4*)(x + (size_t)row * CC + lane * 4);
    float ss = v.x * v.x + v.y * v.y + v.z * v.z + v.w * v.w;
    #pragma unroll
    for (int off = 32; off > 0; off >>= 1) ss += __shfl_down(ss, off, 64);
    if (lane == 0) invn[row] = 1.0f / sqrtf(ss);
}

// top-k ordering predicate matching jax.lax.top_k: value desc, ties -> smaller index
__device__ __forceinline__ bool knn_better(float v, int j, float v2, int j2) {
    return (v > v2) || (v == v2 && j < j2);
}

// insert candidate into sorted-descending top-4 (registers, fully unrolled)
__device__ __forceinline__ void knn_insert(float v, int j, float (&tv)[4], int (&tj)[4]) {
    if (knn_better(v, j, tv[3], tj[3])) {
        tv[3] = v; tj[3] = j;
        #pragma unroll
        for (int s = 3; s > 0; --s) {
            if (knn_better(tv[s], tj[s], tv[s - 1], tj[s - 1])) {
                float fv = tv[s]; tv[s] = tv[s - 1]; tv[s - 1] = fv;
                int   fj = tj[s]; tj[s] = tj[s - 1]; tj[s - 1] = fj;
            }
        }
    }
}

// ---------------------------------------------------------------------------
// Kernel 2: 64x128 tile, 4x8 per-thread, broadcast-heavy LDS reads,
// shfl-butterfly top-4 merge over the 16 cg lanes.
// ---------------------------------------------------------------------------
__global__ __launch_bounds__(256, 2) void knn_main_kernel(const float* __restrict__ x,
                                                          const float* __restrict__ invn,
                                                          float* __restrict__ out) {
    __shared__ __align__(16) float As[TI * LW];   //  9.0 KB
    __shared__ __align__(16) float Bs[TJ * LW];   // 18.0 KB  (27.6 KB total)

    const int tid = threadIdx.x;
    const int b   = blockIdx.x >> 6;         // 64 i-tiles per batch
    const int it  = blockIdx.x & 63;
    const int i0  = it * TI;
    const float* xb   = x    + (size_t)b * NN * CC;
    const float* invb = invn + (size_t)b * NN;
    const int rg = tid >> 4;                 // 0..15 ; wave = {4 rg values} x 16 cg
    const int cg = tid & 15;                 // 0..15

    float vni[4];
    #pragma unroll
    for (int ri = 0; ri < 4; ++ri) vni[ri] = invb[i0 + rg + 16 * ri];

    // per-thread sorted top-4 per owned row, kept for the whole kernel (32 regs)
    float tv[4][4];
    int   tjx[4][4];
    #pragma unroll
    for (int ri = 0; ri < 4; ++ri)
        #pragma unroll
        for (int s = 0; s < 4; ++s) { tv[ri][s] = -INFINITY; tjx[ri][s] = INT_MAX; }

    // staging: 192 rows (A:64 + B:128) x 8 float4 = 1536 float4 / 256 thr = 6 each
    const int s_row = tid >> 3;              // 0..31 (base row, step 32 per chunk)
    const int s_k4  = tid & 7;

    for (int jt = 0; jt < NN / TJ; ++jt) {   // 32 j-tiles
        const int j0 = jt * TJ;
        float vnj[8];
        #pragma unroll
        for (int ci = 0; ci < 8; ++ci) vnj[ci] = invb[j0 + cg + 16 * ci];

        float acc[4][8];
        #pragma unroll
        for (int ri = 0; ri < 4; ++ri)
            #pragma unroll
            for (int ci = 0; ci < 8; ++ci) acc[ri][ci] = 0.0f;

        for (int kt = 0; kt < CC / TK; ++kt) {   // 8 k-chunks
            const int ko = kt * TK + s_k4 * 4;
            __syncthreads();   // prior-iter LDS reads done before overwrite
            // stage A (rows 0..63 of tile) and B (rows 0..127): 6 float4/thread
            #pragma unroll
            for (int l = 0; l < 2; ++l) {
                const int r = s_row + 32 * l;              // 0..63 -> A
                const float4 v = *(const float4*)(xb + (size_t)(i0 + r) * CC + ko);
                *(float4*)(As + r * LW + s_k4 * 4) = v;
            }
            #pragma unroll
            for (int l = 0; l < 4; ++l) {
                const int r = s_row + 32 * l;              // 0..127 -> B
                const float4 v = *(const float4*)(xb + (size_t)(j0 + r) * CC + ko);
                *(float4*)(Bs + r * LW + s_k4 * 4) = v;
            }
            __syncthreads();

            #pragma unroll
            for (int k4 = 0; k4 < TK / 4; ++k4) {
                float4 b4[8];
                #pragma unroll
                for (int ci = 0; ci < 8; ++ci)     // 16 distinct addrs x 4-bcast
                    b4[ci] = *(const float4*)(Bs + (cg + 16 * ci) * LW + k4 * 4);
                #pragma unroll
                for (int ri = 0; ri < 4; ++ri) {   // 4 distinct addrs x 16-bcast
                    const float4 a4 = *(const float4*)(As + (rg + 16 * ri) * LW + k4 * 4);
                    #pragma unroll
                    for (int ci = 0; ci < 8; ++ci) {
                        acc[ri][ci] = fmaf(a4.x, b4[ci].x, acc[ri][ci]);
                        acc[ri][ci] = fmaf(a4.y, b4[ci].y, acc[ri][ci]);
                        acc[ri][ci] = fmaf(a4.z, b4[ci].z, acc[ri][ci]);
                        acc[ri][ci] = fmaf(a4.w, b4[ci].w, acc[ri][ci]);
                    }
                }
            }
        }

        // ---- top-k update for this j-tile (registers only) ----
        #pragma unroll
        for (int ri = 0; ri < 4; ++ri) {
            const int ig = i0 + rg + 16 * ri;
            #pragma unroll
            for (int ci = 0; ci < 8; ++ci) {
                const int jg = j0 + cg + 16 * ci;
                if (jg == ig) continue;            // diagonal = -inf in reference
                const float v = acc[ri][ci] * vni[ri] * vnj[ci];
                knn_insert(v, jg, tv[ri], tjx[ri]);
            }
        }
    }

    // ---- butterfly merge across the 16 cg lanes (low 4 lane bits) ----
    #pragma unroll
    for (int m = 1; m <= 8; m <<= 1) {
        #pragma unroll
        for (int ri = 0; ri < 4; ++ri) {
            float pv[4]; int pj[4];
            #pragma unroll
            for (int s = 0; s < 4; ++s) {
                pv[s] = __shfl_xor(tv[ri][s],  m, 64);
                pj[s] = __shfl_xor(tjx[ri][s], m, 64);
            }
            #pragma unroll
            for (int s = 0; s < 4; ++s) knn_insert(pv[s], pj[s], tv[ri], tjx[ri]);
        }
    }

    // lane cg==0 of each rg holds the final top-4 for its 4 rows
    if (cg == 0) {
        float* o_src = out + (size_t)b * 2 * NKE;
        float* o_tgt = o_src + NKE;
        float* o_w   = out + (size_t)BATCH * 2 * NKE + (size_t)b * NKE;
        #pragma unroll
        for (int ri = 0; ri < 4; ++ri) {
            const int ig = i0 + rg + 16 * ri;
            #pragma unroll
            for (int s = 0; s < 4; ++s) {
                o_src[ig * KNN_K + s] = (float)ig;
                o_tgt[ig * KNN_K + s] = (float)tjx[ri][s];
                o_w[ig * KNN_K + s]   = tv[ri][s];
            }
        }
    }
}

extern "C" void kernel_launch(void* const* d_in, const int* in_sizes, int n_in,
                              void* d_out, int out_size, void* d_ws, size_t ws_size,
                              hipStream_t stream) {
    const float* x    = (const float*)d_in[0];
    float*       out  = (float*)d_out;
    float*       invn = (float*)d_ws;   // 8*4096 floats = 128 KB scratch

    knn_norm_kernel<<<(BATCH * NN) / 4, 256, 0, stream>>>(x, invn);
    knn_main_kernel<<<BATCH * (NN / TI), 256, 0, stream>>>(x, invn, out);
}